// Round 14
// baseline (142.957 us; speedup 1.0000x reference)
//
#include <hip/hip_runtime.h>

namespace {
constexpr int DEPTH    = 11;
constexpr int IN_W     = 768;
constexpr int LEAF_W   = 16;
constexpr int OUT_W    = 768;
constexpr int N_NODES  = (1 << DEPTH) - 1;   // 2047
constexpr int N_LEAVES = (1 << DEPTH);       // 2048
constexpr int BATCH    = 8192;
constexpr int G        = 4;                  // same-leaf samples per wave
constexpr int MAX_TASKS = (BATCH + (G - 1) * N_LEAVES) / G;  // 3584
}

// ---------------- Kernel A: tree routing (one wave per sample) ----------------
// fp64 accumulation keeps decision-boundary error (~3e-8) far below the fp32
// numpy reference's own rounding (~1e-7) -> routing decisions match.
__global__ __launch_bounds__(256) void fff_route(
    const float* __restrict__ x,
    const float* __restrict__ nw,
    const float* __restrict__ nb,
    int* __restrict__ leaf_of,
    int* __restrict__ rank_of,
    int* __restrict__ cnt)
{
    const int lane = threadIdx.x & 63;
    const int s    = (int)((blockIdx.x * blockDim.x + threadIdx.x) >> 6);

    const float* xp = x + (size_t)s * IN_W + lane * 12;
    const float4 xv0 = *(const float4*)(xp + 0);
    const float4 xv1 = *(const float4*)(xp + 4);
    const float4 xv2 = *(const float4*)(xp + 8);
    const float xs[12] = {xv0.x, xv0.y, xv0.z, xv0.w,
                          xv1.x, xv1.y, xv1.z, xv1.w,
                          xv2.x, xv2.y, xv2.z, xv2.w};

    int node = 0;
    #pragma unroll 1
    for (int d = 0; d < DEPTH; ++d) {
        const float* wp = nw + (size_t)node * IN_W + lane * 12;
        const float4 a0 = *(const float4*)(wp + 0);
        const float4 a1 = *(const float4*)(wp + 4);
        const float4 a2 = *(const float4*)(wp + 8);
        const float wa[12] = {a0.x, a0.y, a0.z, a0.w,
                              a1.x, a1.y, a1.z, a1.w,
                              a2.x, a2.y, a2.z, a2.w};
        double acc = 0.0;
        #pragma unroll
        for (int j = 0; j < 12; ++j)
            acc = fma((double)wa[j], (double)xs[j], acc);
        #pragma unroll
        for (int off = 32; off > 0; off >>= 1)
            acc += __shfl_xor(acc, off, 64);
        const double score = acc + (double)nb[node];
        node = 2 * node + 1 + (score >= 0.0 ? 1 : 0);
    }
    const int leaf = node - N_NODES;

    if (lane == 0) {
        leaf_of[s] = leaf;
        rank_of[s] = atomicAdd(&cnt[leaf], 1);
    }
}

// ------- Kernel B: dual exclusive scan (sample offsets + group offsets) -------
__global__ void fff_scan(const int* __restrict__ cnt,
                         int* __restrict__ off,
                         int* __restrict__ goff,
                         int* __restrict__ ntasks)
{
    const int lane = threadIdx.x & 63;        // launched with 64 threads
    const int base = lane * (N_LEAVES / 64);  // 32 leaves per lane
    int c[N_LEAVES / 64], gl[N_LEAVES / 64];
    int s1 = 0, s2 = 0;
    #pragma unroll
    for (int i = 0; i < N_LEAVES / 64; ++i) {
        c[i] = cnt[base + i]; s1 += c[i];
        gl[i] = (c[i] + G - 1) / G; s2 += gl[i];
    }
    int v1 = s1, v2 = s2;
    #pragma unroll
    for (int d = 1; d < 64; d <<= 1) {
        int u1 = __shfl_up(v1, d, 64);
        int u2 = __shfl_up(v2, d, 64);
        if (lane >= d) { v1 += u1; v2 += u2; }
    }
    int r1 = v1 - s1, r2 = v2 - s2;
    #pragma unroll
    for (int i = 0; i < N_LEAVES / 64; ++i) {
        off[base + i]  = r1; r1 += c[i];
        goff[base + i] = r2; r2 += gl[i];
    }
    if (lane == 63) *ntasks = v2;
}

// ---------------- Kernel C: scatter samples into leaf-sorted order ----------------
__global__ __launch_bounds__(256) void fff_scatter(
    const int* __restrict__ leaf_of, const int* __restrict__ rank_of,
    const int* __restrict__ off, int* __restrict__ sorted)
{
    const int s = blockIdx.x * blockDim.x + threadIdx.x;
    if (s < BATCH) sorted[off[leaf_of[s]] + rank_of[s]] = s;
}

// ------- Kernel C2: emit per-group tasks {start, n, leaf} (one thread/leaf) -------
__global__ __launch_bounds__(256) void fff_tasks(
    const int* __restrict__ cnt, const int* __restrict__ off,
    const int* __restrict__ goff, int4* __restrict__ tasks)
{
    const int l = blockIdx.x * blockDim.x + threadIdx.x;
    if (l < N_LEAVES) {
        int n = cnt[l], o = off[l];
        int g0 = goff[l];
        for (int j = 0; n > 0; ++j, n -= G, o += G)
            tasks[g0 + j] = make_int4(o, n < G ? n : G, l, 0);
    }
}

// scheduling fence: pins burst order so load burst N+1 issues BEFORE the FMAs
// of burst N (double-buffer overlap), while ALL s_waitcnt insertion stays
// compiler-owned (correct by construction -- the R9-R12 hand-counted-vmcnt
// corruption cannot happen with plain loads).
#define SB() __builtin_amdgcn_sched_barrier(0)

__device__ __forceinline__ void fma_row16(float xk, const float4& a, const float4& b,
                                          const float4& c, const float4& d,
                                          float (&h)[LEAF_W]) {
    h[0] = fmaf(xk, a.x, h[0]);  h[1] = fmaf(xk, a.y, h[1]);
    h[2] = fmaf(xk, a.z, h[2]);  h[3] = fmaf(xk, a.w, h[3]);
    h[4] = fmaf(xk, b.x, h[4]);  h[5] = fmaf(xk, b.y, h[5]);
    h[6] = fmaf(xk, b.z, h[6]);  h[7] = fmaf(xk, b.w, h[7]);
    h[8] = fmaf(xk, c.x, h[8]);  h[9] = fmaf(xk, c.y, h[9]);
    h[10]= fmaf(xk, c.z, h[10]); h[11]= fmaf(xk, c.w, h[11]);
    h[12]= fmaf(xk, d.x, h[12]); h[13]= fmaf(xk, d.y, h[13]);
    h[14]= fmaf(xk, d.z, h[14]); h[15]= fmaf(xk, d.w, h[15]);
}
__device__ __forceinline__ void fma_row12(float hl, const float4& a, const float4& b,
                                          const float4& c, float (&oa)[12]) {
    oa[0] = fmaf(hl, a.x, oa[0]);  oa[1] = fmaf(hl, a.y, oa[1]);
    oa[2] = fmaf(hl, a.z, oa[2]);  oa[3] = fmaf(hl, a.w, oa[3]);
    oa[4] = fmaf(hl, b.x, oa[4]);  oa[5] = fmaf(hl, b.y, oa[5]);
    oa[6] = fmaf(hl, b.z, oa[6]);  oa[7] = fmaf(hl, b.w, oa[7]);
    oa[8] = fmaf(hl, c.x, oa[8]);  oa[9] = fmaf(hl, c.y, oa[9]);
    oa[10]= fmaf(hl, c.z, oa[10]); oa[11]= fmaf(hl, c.w, oa[11]);
}

// x element r of sample g (g,r literals -> folds to a single register)
#define XK(g, r) ( ((r)&3)==0 ? xq[g][(r)>>2].x : ((r)&3)==1 ? xq[g][(r)>>2].y : \
                   ((r)&3)==2 ? xq[g][(r)>>2].z : xq[g][(r)>>2].w )

// ---- Kernel D: one wave per task (<=4 same-leaf samples), dbuf'd bursts ----
// Grouping cuts requested bytes 3x (R8's bottleneck: 7.6 TB/s service rate);
// double-buffered 2-row bursts keep 16 loads in flight continuously (R13's
// bottleneck: serial bursts drained per stage). Plain C++ loads throughout.
__global__ __launch_bounds__(256, 2) void fff_mlp4d(
    const float* __restrict__ x,
    const float* __restrict__ w1,
    const float* __restrict__ b1,
    const float* __restrict__ w2,
    const int* __restrict__ sorted,
    const int4* __restrict__ tasks,
    const int* __restrict__ ntasks_p,
    float* __restrict__ out)
{
    const int lane = threadIdx.x & 63;
    // XCD-bijective swizzle: 896 blocks = 8 XCDs x 112 contiguous vblocks
    const int vb = (int)((blockIdx.x & 7) * (gridDim.x >> 3) + (blockIdx.x >> 3));
    const int t  = vb * 4 + (int)(threadIdx.x >> 6);
    const int nt = *ntasks_p;
    if (t >= nt) return;

    const int4 task = tasks[t];
    const int start = __builtin_amdgcn_readfirstlane(task.x);
    const int n     = __builtin_amdgcn_readfirstlane(task.y);
    const int leaf  = __builtin_amdgcn_readfirstlane(task.z);

    int sidx[G];
    #pragma unroll
    for (int g = 0; g < G; ++g)
        sidx[g] = __builtin_amdgcn_readfirstlane(sorted[start + (g < n ? g : n - 1)]);

    const float* w1p = w1 + (size_t)leaf * (IN_W * LEAF_W) + (size_t)lane * 12 * LEAF_W;
    const float* w2p = w2 + (size_t)leaf * (LEAF_W * OUT_W) + lane * 12;

    // ---- x loads: 12 loads issued with the L1 prologue ----
    float4 xq[G][3];
    #pragma unroll
    for (int g = 0; g < G; ++g) {
        const float* xp = x + (size_t)sidx[g] * IN_W + lane * 12;
        xq[g][0] = *(const float4*)(xp + 0);
        xq[g][1] = *(const float4*)(xp + 4);
        xq[g][2] = *(const float4*)(xp + 8);
    }

    float h[G][LEAF_W];
    #pragma unroll
    for (int g = 0; g < G; ++g)
        #pragma unroll
        for (int l = 0; l < LEAF_W; ++l) h[g][l] = 0.f;

    float4 WA[2][4], WB[2][4];   // two 2-row L1 buffers (32 VGPR each)
    float4 VA[2][3], VB[2][3];   // two 2-row L2 buffers (24 VGPR each)

#define L1_LOADB(r0, B) do { \
    _Pragma("unroll") \
    for (int j = 0; j < 2; ++j) { \
        const float* rp = w1p + ((r0) + j) * LEAF_W; \
        B[j][0] = *(const float4*)(rp + 0);  B[j][1] = *(const float4*)(rp + 4); \
        B[j][2] = *(const float4*)(rp + 8);  B[j][3] = *(const float4*)(rp + 12); \
    } } while (0)
#define L1_FMAB(r0, B) do { \
    _Pragma("unroll") \
    for (int j = 0; j < 2; ++j) { \
        fma_row16(XK(0,(r0)+j), B[j][0], B[j][1], B[j][2], B[j][3], h[0]); \
        fma_row16(XK(1,(r0)+j), B[j][0], B[j][1], B[j][2], B[j][3], h[1]); \
        fma_row16(XK(2,(r0)+j), B[j][0], B[j][1], B[j][2], B[j][3], h[2]); \
        fma_row16(XK(3,(r0)+j), B[j][0], B[j][1], B[j][2], B[j][3], h[3]); \
    } } while (0)
#define L2_LOADB(r0, B) do { \
    _Pragma("unroll") \
    for (int j = 0; j < 2; ++j) { \
        const float* rp = w2p + (size_t)((r0) + j) * OUT_W; \
        B[j][0] = *(const float4*)(rp + 0); B[j][1] = *(const float4*)(rp + 4); \
        B[j][2] = *(const float4*)(rp + 8); \
    } } while (0)
#define L2_FMAB(r0, B) do { \
    _Pragma("unroll") \
    for (int j = 0; j < 2; ++j) { \
        fma_row12(h[0][(r0)+j], B[j][0], B[j][1], B[j][2], oa[0]); \
        fma_row12(h[1][(r0)+j], B[j][0], B[j][1], B[j][2], oa[1]); \
        fma_row12(h[2][(r0)+j], B[j][0], B[j][1], B[j][2], oa[2]); \
        fma_row12(h[3][(r0)+j], B[j][0], B[j][1], B[j][2], oa[3]); \
    } } while (0)

    // ---- layer 1: 12 rows as 6 double-buffered bursts of 2 rows ----
    // steady state: 16 loads outstanding; compiler emits counted vmcnt waits.
    L1_LOADB(0, WA); SB();
    L1_LOADB(2, WB); SB();
    L1_FMAB(0, WA);  SB(); L1_LOADB(4,  WA); SB();
    L1_FMAB(2, WB);  SB(); L1_LOADB(6,  WB); SB();
    L1_FMAB(4, WA);  SB(); L1_LOADB(8,  WA); SB();
    L1_FMAB(6, WB);  SB(); L1_LOADB(10, WB); SB();
    L1_FMAB(8, WA);  SB(); L2_LOADB(0,  VA); SB();   // prefetch L2 rows 0,1
    L1_FMAB(10, WB); SB();

    // butterfly reduce across 64 lanes (identical result on all lanes);
    // VA's loads fly under this shuffle chain
    #pragma unroll
    for (int g = 0; g < G; ++g)
        #pragma unroll
        for (int l = 0; l < LEAF_W; ++l) {
            float v = h[g][l];
            #pragma unroll
            for (int o2 = 32; o2 > 0; o2 >>= 1) v += __shfl_xor(v, o2, 64);
            h[g][l] = v;
        }
    const float* b1p = b1 + (size_t)leaf * LEAF_W;
    #pragma unroll
    for (int l = 0; l < LEAF_W; ++l) {
        const float bl = b1p[l];
        #pragma unroll
        for (int g = 0; g < G; ++g) h[g][l] = fmaxf(h[g][l] + bl, 0.f);
    }

    float oa[G][12];
    #pragma unroll
    for (int g = 0; g < G; ++g)
        #pragma unroll
        for (int j = 0; j < 12; ++j) oa[g][j] = 0.f;

    // ---- layer 2: 16 rows as 8 double-buffered bursts of 2 rows ----
    L2_LOADB(2, VB);  SB(); L2_FMAB(0, VA);  SB();
    L2_LOADB(4, VA);  SB(); L2_FMAB(2, VB);  SB();
    L2_LOADB(6, VB);  SB(); L2_FMAB(4, VA);  SB();
    L2_LOADB(8, VA);  SB(); L2_FMAB(6, VB);  SB();
    L2_LOADB(10, VB); SB(); L2_FMAB(8, VA);  SB();
    L2_LOADB(12, VA); SB(); L2_FMAB(10, VB); SB();
    L2_LOADB(14, VB); SB(); L2_FMAB(12, VA); SB();
    L2_FMAB(14, VB);  SB();

    #pragma unroll
    for (int g = 0; g < G; ++g) {
        if (g < n) {   // wave-uniform guard
            float* op = out + (size_t)sidx[g] * OUT_W + lane * 12;
            *(float4*)(op + 0) = make_float4(oa[g][0], oa[g][1], oa[g][2],  oa[g][3]);
            *(float4*)(op + 4) = make_float4(oa[g][4], oa[g][5], oa[g][6],  oa[g][7]);
            *(float4*)(op + 8) = make_float4(oa[g][8], oa[g][9], oa[g][10], oa[g][11]);
        }
    }

#undef L1_LOADB
#undef L1_FMAB
#undef L2_LOADB
#undef L2_FMAB
}

extern "C" void kernel_launch(void* const* d_in, const int* in_sizes, int n_in,
                              void* d_out, int out_size, void* d_ws, size_t ws_size,
                              hipStream_t stream) {
    const float* x  = (const float*)d_in[0];
    const float* nw = (const float*)d_in[1];
    const float* nb = (const float*)d_in[2];
    const float* w1 = (const float*)d_in[3];
    const float* b1 = (const float*)d_in[4];
    const float* w2 = (const float*)d_in[5];
    float* o        = (float*)d_out;

    // ws (ints): cnt[2048] off[2048] goff[2048] ntasks[8] leaf[8192] rank[8192]
    //            sorted[8192] | tasks int4[3584]
    int* cnt    = (int*)d_ws;
    int* off    = cnt + N_LEAVES;
    int* goff   = off + N_LEAVES;
    int* ntasks = goff + N_LEAVES;
    int* leaf   = ntasks + 8;
    int* rank   = leaf + BATCH;
    int* sorted = rank + BATCH;
    int4* tasks = (int4*)(sorted + BATCH);

    (void)hipMemsetAsync(cnt, 0, N_LEAVES * sizeof(int), stream);

    fff_route  <<<dim3(BATCH / 4),    dim3(256), 0, stream>>>(x, nw, nb, leaf, rank, cnt);
    fff_scan   <<<dim3(1),            dim3(64),  0, stream>>>(cnt, off, goff, ntasks);
    fff_scatter<<<dim3(BATCH/256),    dim3(256), 0, stream>>>(leaf, rank, off, sorted);
    fff_tasks  <<<dim3(N_LEAVES/256), dim3(256), 0, stream>>>(cnt, off, goff, tasks);
    fff_mlp4d  <<<dim3(MAX_TASKS/4),  dim3(256), 0, stream>>>(
        x, w1, b1, w2, sorted, tasks, ntasks, o);
}

// Round 15
// 113.196 us; speedup vs baseline: 1.2629x; 1.2629x over previous
//
#include <hip/hip_runtime.h>

namespace {
constexpr int DEPTH    = 11;
constexpr int IN_W     = 768;
constexpr int LEAF_W   = 16;
constexpr int OUT_W    = 768;
constexpr int N_NODES  = (1 << DEPTH) - 1;   // 2047
constexpr int N_LEAVES = (1 << DEPTH);       // 2048
constexpr int BATCH    = 8192;
constexpr int G        = 4;                  // same-leaf samples per wave
constexpr int MAX_TASKS = (BATCH + (G - 1) * N_LEAVES) / G;  // 3584
}

// ---------------- Kernel A: tree routing (one wave per sample) ----------------
// COALESCED: lane L reads float-chunk 4L of each 3 KB row (16 lines/instr, was
// 64 lines/instr with the lane*12 layout -- the session-long hidden cost).
// fp64 accumulation keeps decision error far below the fp32 reference's own
// rounding -> routing decisions match.
__global__ __launch_bounds__(256) void fff_route(
    const float* __restrict__ x,
    const float* __restrict__ nw,
    const float* __restrict__ nb,
    int* __restrict__ leaf_of,
    int* __restrict__ rank_of,
    int* __restrict__ cnt)
{
    const int lane = threadIdx.x & 63;
    const int s    = (int)((blockIdx.x * blockDim.x + threadIdx.x) >> 6);

    const float* xp = x + (size_t)s * IN_W + 4 * lane;
    const float4 xv0 = *(const float4*)(xp + 0);
    const float4 xv1 = *(const float4*)(xp + 256);
    const float4 xv2 = *(const float4*)(xp + 512);

    int node = 0;
    #pragma unroll 1
    for (int d = 0; d < DEPTH; ++d) {
        const float* wp = nw + (size_t)node * IN_W + 4 * lane;
        const float4 a0 = *(const float4*)(wp + 0);
        const float4 a1 = *(const float4*)(wp + 256);
        const float4 a2 = *(const float4*)(wp + 512);
        double acc = 0.0;
        acc = fma((double)a0.x, (double)xv0.x, acc);
        acc = fma((double)a0.y, (double)xv0.y, acc);
        acc = fma((double)a0.z, (double)xv0.z, acc);
        acc = fma((double)a0.w, (double)xv0.w, acc);
        acc = fma((double)a1.x, (double)xv1.x, acc);
        acc = fma((double)a1.y, (double)xv1.y, acc);
        acc = fma((double)a1.z, (double)xv1.z, acc);
        acc = fma((double)a1.w, (double)xv1.w, acc);
        acc = fma((double)a2.x, (double)xv2.x, acc);
        acc = fma((double)a2.y, (double)xv2.y, acc);
        acc = fma((double)a2.z, (double)xv2.z, acc);
        acc = fma((double)a2.w, (double)xv2.w, acc);
        #pragma unroll
        for (int off = 32; off > 0; off >>= 1)
            acc += __shfl_xor(acc, off, 64);
        const double score = acc + (double)nb[node];
        node = 2 * node + 1 + (score >= 0.0 ? 1 : 0);
    }
    const int leaf = node - N_NODES;

    if (lane == 0) {
        leaf_of[s] = leaf;
        rank_of[s] = atomicAdd(&cnt[leaf], 1);
    }
}

// ------- Kernel B: dual exclusive scan (sample offsets + group offsets) -------
__global__ void fff_scan(const int* __restrict__ cnt,
                         int* __restrict__ off,
                         int* __restrict__ goff,
                         int* __restrict__ ntasks)
{
    const int lane = threadIdx.x & 63;        // launched with 64 threads
    const int base = lane * (N_LEAVES / 64);  // 32 leaves per lane
    int c[N_LEAVES / 64], gl[N_LEAVES / 64];
    int s1 = 0, s2 = 0;
    #pragma unroll
    for (int i = 0; i < N_LEAVES / 64; ++i) {
        c[i] = cnt[base + i]; s1 += c[i];
        gl[i] = (c[i] + G - 1) / G; s2 += gl[i];
    }
    int v1 = s1, v2 = s2;
    #pragma unroll
    for (int d = 1; d < 64; d <<= 1) {
        int u1 = __shfl_up(v1, d, 64);
        int u2 = __shfl_up(v2, d, 64);
        if (lane >= d) { v1 += u1; v2 += u2; }
    }
    int r1 = v1 - s1, r2 = v2 - s2;
    #pragma unroll
    for (int i = 0; i < N_LEAVES / 64; ++i) {
        off[base + i]  = r1; r1 += c[i];
        goff[base + i] = r2; r2 += gl[i];
    }
    if (lane == 63) *ntasks = v2;
}

// ---------------- Kernel C: scatter samples into leaf-sorted order ----------------
__global__ __launch_bounds__(256) void fff_scatter(
    const int* __restrict__ leaf_of, const int* __restrict__ rank_of,
    const int* __restrict__ off, int* __restrict__ sorted)
{
    const int s = blockIdx.x * blockDim.x + threadIdx.x;
    if (s < BATCH) sorted[off[leaf_of[s]] + rank_of[s]] = s;
}

// ------- Kernel C2: emit per-group tasks {start, n, leaf} (one thread/leaf) -------
__global__ __launch_bounds__(256) void fff_tasks(
    const int* __restrict__ cnt, const int* __restrict__ off,
    const int* __restrict__ goff, int4* __restrict__ tasks)
{
    const int l = blockIdx.x * blockDim.x + threadIdx.x;
    if (l < N_LEAVES) {
        int n = cnt[l], o = off[l];
        int g0 = goff[l];
        for (int j = 0; n > 0; ++j, n -= G, o += G)
            tasks[g0 + j] = make_int4(o, n < G ? n : G, l, 0);
    }
}

// scheduling fence: pins burst boundaries; waitcnts stay compiler-owned.
#define SB() __builtin_amdgcn_sched_barrier(0)

// ---- Kernel D: one wave per task (<=4 same-leaf samples), ALL-COALESCED ----
// w1 load k: 1 KB contiguous = rows 16k..16k+15; lane L holds
// w1[16k+(L>>2)][4(L&3)..+3]. x is staged in a wave-private LDS slice and read
// back as a conflict-free 16-bank broadcast. h reduced per 4-lane column class
// (shfl_xor 4/8/16/32), then shfl-broadcast into the w2 pass, which is also
// fully coalesced (lane L owns output cols {4L, 256+4L, 512+4L}).
__global__ __launch_bounds__(256, 2) void fff_mlp_co(
    const float* __restrict__ x,
    const float* __restrict__ w1,
    const float* __restrict__ b1,
    const float* __restrict__ w2,
    const int* __restrict__ sorted,
    const int4* __restrict__ tasks,
    const int* __restrict__ ntasks_p,
    float* __restrict__ out)
{
    __shared__ float xbuf[4][G][IN_W];   // 48 KB; wave-private slices -> no barriers

    const int lane = threadIdx.x & 63;
    const int wv   = (int)(threadIdx.x >> 6);
    const int rq   = lane >> 2;          // row-in-group 0..15
    // XCD-bijective swizzle: 896 blocks = 8 XCDs x 112 contiguous vblocks
    const int vb = (int)((blockIdx.x & 7) * (gridDim.x >> 3) + (blockIdx.x >> 3));
    const int t  = vb * 4 + wv;
    const int nt = *ntasks_p;
    if (t >= nt) return;

    const int4 task = tasks[t];
    const int start = __builtin_amdgcn_readfirstlane(task.x);
    const int n     = __builtin_amdgcn_readfirstlane(task.y);
    const int leaf  = __builtin_amdgcn_readfirstlane(task.z);

    int sidx[G];
    #pragma unroll
    for (int g = 0; g < G; ++g)
        sidx[g] = __builtin_amdgcn_readfirstlane(sorted[start + (g < n ? g : n - 1)]);

    const float* w1g = w1 + (size_t)leaf * (IN_W * LEAF_W);   // uniform (SGPR base)
    const float* w2g = w2 + (size_t)leaf * (LEAF_W * OUT_W);
    const float* b1g = b1 + (size_t)leaf * LEAF_W;

    // ---- stage x into this wave's LDS slice (coalesced loads, b128 writes) ----
    float* xw = &xbuf[wv][0][0];
    #pragma unroll
    for (int g = 0; g < G; ++g) {
        const float* xp = x + (size_t)sidx[g] * IN_W + 4 * lane;
        const float4 a = *(const float4*)(xp + 0);
        const float4 b = *(const float4*)(xp + 256);
        const float4 c = *(const float4*)(xp + 512);
        *(float4*)(xw + g * IN_W + 4 * lane + 0)   = a;
        *(float4*)(xw + g * IN_W + 4 * lane + 256) = b;
        *(float4*)(xw + g * IN_W + 4 * lane + 512) = c;
    }
    SB();

    float4 hacc[G];
    #pragma unroll
    for (int g = 0; g < G; ++g) hacc[g] = make_float4(0.f, 0.f, 0.f, 0.f);

    float4 WA[4], WB[4];

#define L1_LOADB(k0, B) do { \
    _Pragma("unroll") \
    for (int j = 0; j < 4; ++j) \
        B[j] = *(const float4*)(w1g + ((k0) + j) * 256 + 4 * lane); \
    } while (0)
#define L1_FMAB(k0, B) do { \
    _Pragma("unroll") \
    for (int j = 0; j < 4; ++j) { \
        const int row = 16 * ((k0) + j) + rq; \
        _Pragma("unroll") \
        for (int g = 0; g < G; ++g) { \
            const float xv = xw[g * IN_W + row]; \
            hacc[g].x = fmaf(xv, B[j].x, hacc[g].x); \
            hacc[g].y = fmaf(xv, B[j].y, hacc[g].y); \
            hacc[g].z = fmaf(xv, B[j].z, hacc[g].z); \
            hacc[g].w = fmaf(xv, B[j].w, hacc[g].w); \
        } \
    } } while (0)

    // ---- layer 1: 48 coalesced loads as 12 double-buffered bursts of 4 ----
    L1_LOADB(0, WA); SB();
    L1_LOADB(4, WB); SB();
    L1_FMAB(0,  WA); SB(); L1_LOADB(8,  WA); SB();
    L1_FMAB(4,  WB); SB(); L1_LOADB(12, WB); SB();
    L1_FMAB(8,  WA); SB(); L1_LOADB(16, WA); SB();
    L1_FMAB(12, WB); SB(); L1_LOADB(20, WB); SB();
    L1_FMAB(16, WA); SB(); L1_LOADB(24, WA); SB();
    L1_FMAB(20, WB); SB(); L1_LOADB(28, WB); SB();
    L1_FMAB(24, WA); SB(); L1_LOADB(32, WA); SB();
    L1_FMAB(28, WB); SB(); L1_LOADB(36, WB); SB();
    L1_FMAB(32, WA); SB(); L1_LOADB(40, WA); SB();
    L1_FMAB(36, WB); SB(); L1_LOADB(44, WB); SB();
    L1_FMAB(40, WA); SB();
    L1_FMAB(44, WB); SB();

    float4 VA[4], VB[4];
#define L2_LOADB(q0, B) do { \
    _Pragma("unroll") \
    for (int j = 0; j < 4; ++j) { \
        const int q = (q0) + j, l = q / 3, m = q % 3; \
        B[j] = *(const float4*)(w2g + l * OUT_W + m * 256 + 4 * lane); \
    } } while (0)

    // prefetch first two L2 bursts; their latency hides under the reduce
    L2_LOADB(0, VA); SB();
    L2_LOADB(4, VB); SB();

    // ---- reduce h across the 16 lanes of each column class ----
    float hr[G][4];
    #pragma unroll
    for (int g = 0; g < G; ++g) {
        float4 v = hacc[g];
        #pragma unroll
        for (int o2 = 4; o2 < 64; o2 <<= 1) {
            v.x += __shfl_xor(v.x, o2, 64);
            v.y += __shfl_xor(v.y, o2, 64);
            v.z += __shfl_xor(v.z, o2, 64);
            v.w += __shfl_xor(v.w, o2, 64);
        }
        hr[g][0] = v.x; hr[g][1] = v.y; hr[g][2] = v.z; hr[g][3] = v.w;
    }
    // bias + relu: lane's class c = lane&3 owns cols 4c..4c+3
    {
        const float4 bv = *(const float4*)(b1g + 4 * (lane & 3));
        #pragma unroll
        for (int g = 0; g < G; ++g) {
            hr[g][0] = fmaxf(hr[g][0] + bv.x, 0.f);
            hr[g][1] = fmaxf(hr[g][1] + bv.y, 0.f);
            hr[g][2] = fmaxf(hr[g][2] + bv.z, 0.f);
            hr[g][3] = fmaxf(hr[g][3] + bv.w, 0.f);
        }
    }

    float4 oa[G][3];
    #pragma unroll
    for (int g = 0; g < G; ++g)
        #pragma unroll
        for (int m = 0; m < 3; ++m) oa[g][m] = make_float4(0.f, 0.f, 0.f, 0.f);

#define L2_FMAB(q0, B) do { \
    _Pragma("unroll") \
    for (int j = 0; j < 4; ++j) { \
        const int q = (q0) + j, l = q / 3, m = q % 3; \
        _Pragma("unroll") \
        for (int g = 0; g < G; ++g) { \
            const float hb = __shfl(hr[g][l & 3], l >> 2, 64); \
            oa[g][m].x = fmaf(hb, B[j].x, oa[g][m].x); \
            oa[g][m].y = fmaf(hb, B[j].y, oa[g][m].y); \
            oa[g][m].z = fmaf(hb, B[j].z, oa[g][m].z); \
            oa[g][m].w = fmaf(hb, B[j].w, oa[g][m].w); \
        } \
    } } while (0)

    // ---- layer 2: 48 coalesced loads as 12 double-buffered bursts of 4 ----
    L2_FMAB(0,  VA); SB(); L2_LOADB(8,  VA); SB();
    L2_FMAB(4,  VB); SB(); L2_LOADB(12, VB); SB();
    L2_FMAB(8,  VA); SB(); L2_LOADB(16, VA); SB();
    L2_FMAB(12, VB); SB(); L2_LOADB(20, VB); SB();
    L2_FMAB(16, VA); SB(); L2_LOADB(24, VA); SB();
    L2_FMAB(20, VB); SB(); L2_LOADB(28, VB); SB();
    L2_FMAB(24, VA); SB(); L2_LOADB(32, VA); SB();
    L2_FMAB(28, VB); SB(); L2_LOADB(36, VB); SB();
    L2_FMAB(32, VA); SB(); L2_LOADB(40, VA); SB();
    L2_FMAB(36, VB); SB(); L2_LOADB(44, VB); SB();
    L2_FMAB(40, VA); SB();
    L2_FMAB(44, VB); SB();

    // ---- coalesced stores: lane L owns cols {4L, 256+4L, 512+4L} ----
    #pragma unroll
    for (int g = 0; g < G; ++g) {
        if (g < n) {   // wave-uniform guard
            float* op = out + (size_t)sidx[g] * OUT_W + 4 * lane;
            *(float4*)(op + 0)   = oa[g][0];
            *(float4*)(op + 256) = oa[g][1];
            *(float4*)(op + 512) = oa[g][2];
        }
    }

#undef L1_LOADB
#undef L1_FMAB
#undef L2_LOADB
#undef L2_FMAB
}

extern "C" void kernel_launch(void* const* d_in, const int* in_sizes, int n_in,
                              void* d_out, int out_size, void* d_ws, size_t ws_size,
                              hipStream_t stream) {
    const float* x  = (const float*)d_in[0];
    const float* nw = (const float*)d_in[1];
    const float* nb = (const float*)d_in[2];
    const float* w1 = (const float*)d_in[3];
    const float* b1 = (const float*)d_in[4];
    const float* w2 = (const float*)d_in[5];
    float* o        = (float*)d_out;

    // ws (ints): cnt[2048] off[2048] goff[2048] ntasks[8] leaf[8192] rank[8192]
    //            sorted[8192] | tasks int4[3584]
    int* cnt    = (int*)d_ws;
    int* off    = cnt + N_LEAVES;
    int* goff   = off + N_LEAVES;
    int* ntasks = goff + N_LEAVES;
    int* leaf   = ntasks + 8;
    int* rank   = leaf + BATCH;
    int* sorted = rank + BATCH;
    int4* tasks = (int4*)(sorted + BATCH);

    (void)hipMemsetAsync(cnt, 0, N_LEAVES * sizeof(int), stream);

    fff_route  <<<dim3(BATCH / 4),    dim3(256), 0, stream>>>(x, nw, nb, leaf, rank, cnt);
    fff_scan   <<<dim3(1),            dim3(64),  0, stream>>>(cnt, off, goff, ntasks);
    fff_scatter<<<dim3(BATCH/256),    dim3(256), 0, stream>>>(leaf, rank, off, sorted);
    fff_tasks  <<<dim3(N_LEAVES/256), dim3(256), 0, stream>>>(cnt, off, goff, tasks);
    fff_mlp_co <<<dim3(MAX_TASKS/4),  dim3(256), 0, stream>>>(
        x, w1, b1, w2, sorted, tasks, ntasks, o);
}